// Round 18
// baseline (278.948 us; speedup 1.0000x reference)
//
#include <hip/hip_runtime.h>

#define NC 2048
#define D 64
#define H 32

typedef __fp16 h2 __attribute__((ext_vector_type(2)));
typedef unsigned int u32;

#if __has_builtin(__builtin_amdgcn_fdot2)
#define FDOT2(a, b, c) __builtin_amdgcn_fdot2((a), (b), (c), false)
#else
#define FDOT2(a, b, c) ((c) + (float)(a)[0] * (float)(b)[0] + (float)(a)[1] * (float)(b)[1])
#endif
#define BC2(u) __builtin_bit_cast(h2, (u))

// ---- K1: fused fp16-convert (fea -> d_ws) + segment bounds (R17-verified) -
__global__ __launch_bounds__(256) void convert_bounds_kernel(
    const float* __restrict__ atom_feas,
    const int* __restrict__ owner,
    uint2* __restrict__ f16fea,
    int* __restrict__ bounds,
    int n)
{
    const int t = blockIdx.x * 256 + threadIdx.x;
    const int nf4 = n * (D / 4);
    if (t < nf4) {
        const float4 v = ((const float4*)atom_feas)[t];
        uint2 w;
        w.x = __builtin_bit_cast(u32, __builtin_amdgcn_cvt_pkrtz(v.x, v.y));
        w.y = __builtin_bit_cast(u32, __builtin_amdgcn_cvt_pkrtz(v.z, v.w));
        f16fea[t] = w;
    }
    if (t < n) {
        const int o  = owner[t];
        const int op = (t == 0) ? -1 : owner[t - 1];
        for (int g = op + 1; g <= o; ++g) bounds[g] = t;
        if (t == n - 1)
            for (int g = o + 1; g <= NC; ++g) bounds[g] = n;
    }
}

// ---- K2: 2 waves/crystal, in-lane full dot, zero cross-lane in loop ------
// R17 post-mortem: 1 wave/crystal = 2 waves/SIMD -> L2 latency exposed.
// R13 post-mortem: per-atom shfl -> lgkmcnt drain serializes the pipeline.
// R18: lane = (dg = lane>>5, h = lane&31) holds the FULL Wk column h
// (wkh[32] h2 regs) and computes the full 64-dim dot IN-LANE (redundant
// across dg halves, 32 FDOT2); p is born in-lane -> NO shfl, NO DS, NO
// barrier in the loop. acc[32] covers dims dg*32..+31 only. Waves 0/1 of a
// 128-thread block take even/odd atoms of crystal g -> 4096 waves = 4/SIMD.
// Atom rows read directly from fp16 copy (uniform addr -> broadcast, 128B
// per atom, L2-resident 12.8MB). Every lane's running es IS the complete
// denominator for its atoms (all lanes see all its wave's atoms).
// Combine: wave1 -> part[65][77] (20KB REAL+READ array: shapes exactly
// 8 blocks/CU -> 16 waves/CU -> 4 waves/EU -> VGPR cap 128 >= demand ~110,
// per the R4-R9 occupancy law; col 77 -> 13r+h banking, worst 2-way=free),
// one barrier, wave0 adds + stores (2x128B per instr).
__global__ __launch_bounds__(128)
void crystal_kernel(
    const uint4* __restrict__ f16row,   // fp16 fea, 8 uint4 per atom row
    const float* __restrict__ Wk,
    const float* __restrict__ bk,
    const int* __restrict__ bounds,
    float* __restrict__ out)
{
    __shared__ float part[65][77];      // 20020 B

    const int g    = blockIdx.x;
    const int tid  = threadIdx.x;
    const int lane = tid & 63;
    const int wv   = tid >> 6;          // 0 or 1
    const int h    = lane & 31;
    const int dg   = lane >> 5;

    // full Wk column h as packed half2 (32 regs)
    h2 wkh[32];
    #pragma unroll
    for (int j = 0; j < 32; ++j)
        wkh[j] = __builtin_amdgcn_cvt_pkrtz(Wk[(2 * j) * H + h],
                                            Wk[(2 * j + 1) * H + h]);
    const float bkv = bk[h];

    const int s = bounds[g];
    const int e = bounds[g + 1];

    float acc[32];
    #pragma unroll
    for (int j = 0; j < 32; ++j) acc[j] = 0.f;
    float es = 0.f;

    // main loop: wave wv processes atoms s+wv, s+wv+2, ... (interleaved)
    #pragma unroll 2
    for (int a = s + wv; a < e; a += 2) {
        const uint4* rp = f16row + (size_t)a * 8;
        uint4 xx[8];
        #pragma unroll
        for (int j = 0; j < 8; ++j) xx[j] = rp[j];

        // full 64-dim dot, 4 independent chains (in-lane, no cross-lane)
        float q0 = 0.f, q1 = 0.f, q2 = 0.f, q3 = 0.f;
        #pragma unroll
        for (int j = 0; j < 8; ++j) {
            q0 = FDOT2(BC2(xx[j].x), wkh[4 * j + 0], q0);
            q1 = FDOT2(BC2(xx[j].y), wkh[4 * j + 1], q1);
            q2 = FDOT2(BC2(xx[j].z), wkh[4 * j + 2], q2);
            q3 = FDOT2(BC2(xx[j].w), wkh[4 * j + 3], q3);
        }
        const float p = __expf((q0 + q1) + (q2 + q3) + bkv);
        es += p;

        // outer product on THIS lane's dg-half only (4 uint4 = 32 dims)
        #pragma unroll
        for (int j = 0; j < 4; ++j) {
            const uint4 xq = xx[dg * 4 + j];
            const h2 ha = BC2(xq.x);
            const h2 hb = BC2(xq.y);
            const h2 hc = BC2(xq.z);
            const h2 hd = BC2(xq.w);
            acc[8 * j + 0] += (float)ha[0] * p;
            acc[8 * j + 1] += (float)ha[1] * p;
            acc[8 * j + 2] += (float)hb[0] * p;
            acc[8 * j + 3] += (float)hb[1] * p;
            acc[8 * j + 4] += (float)hc[0] * p;
            acc[8 * j + 5] += (float)hc[1] * p;
            acc[8 * j + 6] += (float)hd[0] * p;
            acc[8 * j + 7] += (float)hd[1] * p;
        }
    }

    // ---- cross-wave combine (once per block)
    if (wv == 1) {
        #pragma unroll
        for (int m = 0; m < 32; ++m) part[dg * 32 + m][h] = acc[m];
        if (lane < 32) part[64][lane] = es;
    }
    __syncthreads();
    if (wv == 0) {
        const float den = es + part[64][h];
        const float inv = (den > 0.f) ? 1.0f / den : 0.f;
        float* og = out + (size_t)g * (D * H);
        #pragma unroll
        for (int m = 0; m < 32; ++m)
            og[(dg * 32 + m) * H + h] = (acc[m] + part[dg * 32 + m][h]) * inv;
    }
}

// ---- Fallback (ws too small): known-good fused kernel --------------------
#define CHUNK 64
__global__ __launch_bounds__(256) void fused_kernel(
    const float* __restrict__ atom_feas,
    const float* __restrict__ Wk,
    const float* __restrict__ bk,
    const int* __restrict__ owner,
    float* __restrict__ out,
    int n_atoms)
{
    __shared__ float fea_lds[CHUNK * D];
    __shared__ float w_lds[CHUNK * H];
    __shared__ float wk_lds[D * H];
    __shared__ float bk_lds[H];

    const int g   = blockIdx.x;
    const int tid = threadIdx.x;
    const int h   = tid & 31;
    const int grp = tid >> 5;

    for (int i = tid; i < D * H; i += 256) wk_lds[i] = Wk[i];
    if (tid < H) bk_lds[tid] = bk[tid];

    int lo = 0, hi = n_atoms;
    while (lo < hi) { int mid = (lo + hi) >> 1; if (owner[mid] < g) lo = mid + 1; else hi = mid; }
    const int seg_start = lo;
    hi = n_atoms;
    while (lo < hi) { int mid = (lo + hi) >> 1; if (owner[mid] < g + 1) lo = mid + 1; else hi = mid; }
    const int seg_end = lo;

    float acc[8];
    #pragma unroll
    for (int j = 0; j < 8; ++j) acc[j] = 0.f;
    float ps = 0.f;

    __syncthreads();

    for (int base = seg_start; base < seg_end; base += CHUNK) {
        const int na = min(CHUNK, seg_end - base);
        {
            const int nf4 = na * (D / 4);
            const float4* src = (const float4*)(atom_feas + (size_t)base * D);
            float4* dst = (float4*)fea_lds;
            for (int i = tid; i < nf4; i += 256) dst[i] = src[i];
        }
        __syncthreads();

        for (int pi = tid; pi < na * H; pi += 256) {
            const int aa = pi >> 5;
            const int hh = pi & 31;
            const float* fr = fea_lds + aa * D;
            float wvl = bk_lds[hh];
            #pragma unroll
            for (int k = 0; k < D; k += 4) {
                float4 f = *(const float4*)(fr + k);
                wvl += f.x * wk_lds[(k + 0) * H + hh];
                wvl += f.y * wk_lds[(k + 1) * H + hh];
                wvl += f.z * wk_lds[(k + 2) * H + hh];
                wvl += f.w * wk_lds[(k + 3) * H + hh];
            }
            w_lds[pi] = __expf(wvl);
        }
        __syncthreads();

        for (int aa = 0; aa < na; ++aa) {
            const float p = w_lds[aa * H + h];
            ps += p;
            const float* f = fea_lds + aa * D + grp * 8;
            #pragma unroll
            for (int j = 0; j < 8; ++j) acc[j] += f[j] * p;
        }
        __syncthreads();
    }

    const float inv = (ps > 0.f) ? 1.0f / ps : 0.f;
    float* og = out + (size_t)g * (D * H);
    #pragma unroll
    for (int j = 0; j < 8; ++j) og[(grp * 8 + j) * H + h] = acc[j] * inv;
}

extern "C" void kernel_launch(void* const* d_in, const int* in_sizes, int n_in,
                              void* d_out, int out_size, void* d_ws, size_t ws_size,
                              hipStream_t stream) {
    const float* atom_feas = (const float*)d_in[0];
    const float* Wk        = (const float*)d_in[1];
    const float* bk        = (const float*)d_in[2];
    // d_in[3] = atomic_numbers (unused by the reference)
    const int*   owner     = (const int*)d_in[4];
    const int n_atoms = in_sizes[4];
    float* out = (float*)d_out;

    const size_t bounds_bytes = 16384;
    const size_t f16_bytes = (size_t)n_atoms * D * 2;

    if (ws_size >= bounds_bytes + f16_bytes) {
        int*   bounds = (int*)d_ws;
        uint2* f16fea = (uint2*)((char*)d_ws + bounds_bytes);

        const int nf4 = n_atoms * (D / 4);
        convert_bounds_kernel<<<(nf4 + 255) / 256, 256, 0, stream>>>(
            atom_feas, owner, f16fea, bounds, n_atoms);
        crystal_kernel<<<NC, 128, 0, stream>>>(
            (const uint4*)f16fea, Wk, bk, bounds, out);
    } else {
        fused_kernel<<<NC, 256, 0, stream>>>(atom_feas, Wk, bk, owner, out, n_atoms);
    }
}

// Round 19
// 52.333 us; speedup vs baseline: 5.3302x; 5.3302x over previous
//
#include <hip/hip_runtime.h>

#define NC 2048
#define D 64
#define H 32

typedef __fp16 h2 __attribute__((ext_vector_type(2)));
typedef unsigned int u32;

#if __has_builtin(__builtin_amdgcn_fdot2)
#define FDOT2(a, b, c) __builtin_amdgcn_fdot2((a), (b), (c), false)
#else
#define FDOT2(a, b, c) ((c) + (float)(a)[0] * (float)(b)[0] + (float)(a)[1] * (float)(b)[1])
#endif
#define BC2(u) __builtin_bit_cast(h2, (u))

// ---- K1: fused fp16-convert (fea -> d_ws) + segment bounds (R17-verified) -
__global__ __launch_bounds__(256) void convert_bounds_kernel(
    const float* __restrict__ atom_feas,
    const int* __restrict__ owner,
    uint2* __restrict__ f16fea,
    int* __restrict__ bounds,
    int n)
{
    const int t = blockIdx.x * 256 + threadIdx.x;
    const int nf4 = n * (D / 4);
    if (t < nf4) {
        const float4 v = ((const float4*)atom_feas)[t];
        uint2 w;
        w.x = __builtin_bit_cast(u32, __builtin_amdgcn_cvt_pkrtz(v.x, v.y));
        w.y = __builtin_bit_cast(u32, __builtin_amdgcn_cvt_pkrtz(v.z, v.w));
        f16fea[t] = w;
    }
    if (t < n) {
        const int o  = owner[t];
        const int op = (t == 0) ? -1 : owner[t - 1];
        for (int g = op + 1; g <= o; ++g) bounds[g] = t;
        if (t == n - 1)
            for (int g = o + 1; g <= NC; ++g) bounds[g] = n;
    }
}

// ---- K2: 2 waves/crystal, in-lane full dot, zero cross-lane in loop ------
// R18 post-mortem: xx[dg*4+j] RUNTIME-INDEXED the register array -> SROA
// failed -> whole row buffer in scratch (VGPR 56, WRITE 765MB, 279us).
// R19: NAMED registers x0..x7, dg-half chosen by VALUE ternary (v_cndmask
// x16/atom), all indices compile-time. Design otherwise as R18:
// lane = (dg, h) holds full Wk col h (wkh[32]); full 64-dim dot in-lane
// (no shfl/DS/barrier in loop); acc[32] = lane's dg-half; waves 0/1 take
// even/odd atoms -> 4096 waves = 4/SIMD; rows read from fp16 copy (uniform
// addr broadcast, L2-resident). part[65][77] (20KB real+read) shapes
// 8 blocks/CU -> 4 waves/EU -> VGPR cap 128 >= demand ~111 (occupancy law).
__global__ __launch_bounds__(128)
void crystal_kernel(
    const uint4* __restrict__ f16row,   // fp16 fea, 8 uint4 per atom row
    const float* __restrict__ Wk,
    const float* __restrict__ bk,
    const int* __restrict__ bounds,
    float* __restrict__ out)
{
    __shared__ float part[65][77];      // 20020 B

    const int g    = blockIdx.x;
    const int tid  = threadIdx.x;
    const int lane = tid & 63;
    const int wv   = tid >> 6;          // 0 or 1
    const int h    = lane & 31;
    const int dg   = lane >> 5;

    // full Wk column h as packed half2 (32 regs)
    h2 wkh[32];
    #pragma unroll
    for (int j = 0; j < 32; ++j)
        wkh[j] = __builtin_amdgcn_cvt_pkrtz(Wk[(2 * j) * H + h],
                                            Wk[(2 * j + 1) * H + h]);
    const float bkv = bk[h];

    const int s = bounds[g];
    const int e = bounds[g + 1];

    float acc[32];
    #pragma unroll
    for (int j = 0; j < 32; ++j) acc[j] = 0.f;
    float es = 0.f;

    const bool hi = (dg != 0);

    // main loop: wave wv processes atoms s+wv, s+wv+2, ... (interleaved)
    #pragma unroll 2
    for (int a = s + wv; a < e; a += 2) {
        const uint4* rp = f16row + (size_t)a * 8;
        const uint4 x0 = rp[0], x1 = rp[1], x2 = rp[2], x3 = rp[3];
        const uint4 x4 = rp[4], x5 = rp[5], x6 = rp[6], x7 = rp[7];

        // full 64-dim dot, 4 independent chains (in-lane, no cross-lane)
        float q0 = 0.f, q1 = 0.f, q2 = 0.f, q3 = 0.f;
        q0 = FDOT2(BC2(x0.x), wkh[0],  q0);
        q1 = FDOT2(BC2(x0.y), wkh[1],  q1);
        q2 = FDOT2(BC2(x0.z), wkh[2],  q2);
        q3 = FDOT2(BC2(x0.w), wkh[3],  q3);
        q0 = FDOT2(BC2(x1.x), wkh[4],  q0);
        q1 = FDOT2(BC2(x1.y), wkh[5],  q1);
        q2 = FDOT2(BC2(x1.z), wkh[6],  q2);
        q3 = FDOT2(BC2(x1.w), wkh[7],  q3);
        q0 = FDOT2(BC2(x2.x), wkh[8],  q0);
        q1 = FDOT2(BC2(x2.y), wkh[9],  q1);
        q2 = FDOT2(BC2(x2.z), wkh[10], q2);
        q3 = FDOT2(BC2(x2.w), wkh[11], q3);
        q0 = FDOT2(BC2(x3.x), wkh[12], q0);
        q1 = FDOT2(BC2(x3.y), wkh[13], q1);
        q2 = FDOT2(BC2(x3.z), wkh[14], q2);
        q3 = FDOT2(BC2(x3.w), wkh[15], q3);
        q0 = FDOT2(BC2(x4.x), wkh[16], q0);
        q1 = FDOT2(BC2(x4.y), wkh[17], q1);
        q2 = FDOT2(BC2(x4.z), wkh[18], q2);
        q3 = FDOT2(BC2(x4.w), wkh[19], q3);
        q0 = FDOT2(BC2(x5.x), wkh[20], q0);
        q1 = FDOT2(BC2(x5.y), wkh[21], q1);
        q2 = FDOT2(BC2(x5.z), wkh[22], q2);
        q3 = FDOT2(BC2(x5.w), wkh[23], q3);
        q0 = FDOT2(BC2(x6.x), wkh[24], q0);
        q1 = FDOT2(BC2(x6.y), wkh[25], q1);
        q2 = FDOT2(BC2(x6.z), wkh[26], q2);
        q3 = FDOT2(BC2(x6.w), wkh[27], q3);
        q0 = FDOT2(BC2(x7.x), wkh[28], q0);
        q1 = FDOT2(BC2(x7.y), wkh[29], q1);
        q2 = FDOT2(BC2(x7.z), wkh[30], q2);
        q3 = FDOT2(BC2(x7.w), wkh[31], q3);

        const float p = __expf((q0 + q1) + (q2 + q3) + bkv);
        es += p;

        // VALUE-select this lane's dg-half (v_cndmask x16), static acc idx
        const uint4 y0 = hi ? x4 : x0;
        const uint4 y1 = hi ? x5 : x1;
        const uint4 y2 = hi ? x6 : x2;
        const uint4 y3 = hi ? x7 : x3;
#define OUTQ(Y, base)                                   \
        { const h2 ha = BC2(Y.x); const h2 hb = BC2(Y.y); \
          const h2 hc = BC2(Y.z); const h2 hd = BC2(Y.w); \
          acc[base + 0] += (float)ha[0] * p;              \
          acc[base + 1] += (float)ha[1] * p;              \
          acc[base + 2] += (float)hb[0] * p;              \
          acc[base + 3] += (float)hb[1] * p;              \
          acc[base + 4] += (float)hc[0] * p;              \
          acc[base + 5] += (float)hc[1] * p;              \
          acc[base + 6] += (float)hd[0] * p;              \
          acc[base + 7] += (float)hd[1] * p; }
        OUTQ(y0, 0) OUTQ(y1, 8) OUTQ(y2, 16) OUTQ(y3, 24)
#undef OUTQ
    }

    // ---- cross-wave combine (once per block)
    if (wv == 1) {
        #pragma unroll
        for (int m = 0; m < 32; ++m) part[dg * 32 + m][h] = acc[m];
        if (lane < 32) part[64][lane] = es;
    }
    __syncthreads();
    if (wv == 0) {
        const float den = es + part[64][h];
        const float inv = (den > 0.f) ? 1.0f / den : 0.f;
        float* og = out + (size_t)g * (D * H);
        #pragma unroll
        for (int m = 0; m < 32; ++m)
            og[(dg * 32 + m) * H + h] = (acc[m] + part[dg * 32 + m][h]) * inv;
    }
}

// ---- Fallback (ws too small): known-good fused kernel --------------------
#define CHUNK 64
__global__ __launch_bounds__(256) void fused_kernel(
    const float* __restrict__ atom_feas,
    const float* __restrict__ Wk,
    const float* __restrict__ bk,
    const int* __restrict__ owner,
    float* __restrict__ out,
    int n_atoms)
{
    __shared__ float fea_lds[CHUNK * D];
    __shared__ float w_lds[CHUNK * H];
    __shared__ float wk_lds[D * H];
    __shared__ float bk_lds[H];

    const int g   = blockIdx.x;
    const int tid = threadIdx.x;
    const int h   = tid & 31;
    const int grp = tid >> 5;

    for (int i = tid; i < D * H; i += 256) wk_lds[i] = Wk[i];
    if (tid < H) bk_lds[tid] = bk[tid];

    int lo = 0, hi = n_atoms;
    while (lo < hi) { int mid = (lo + hi) >> 1; if (owner[mid] < g) lo = mid + 1; else hi = mid; }
    const int seg_start = lo;
    hi = n_atoms;
    while (lo < hi) { int mid = (lo + hi) >> 1; if (owner[mid] < g + 1) lo = mid + 1; else hi = mid; }
    const int seg_end = lo;

    float acc[8];
    #pragma unroll
    for (int j = 0; j < 8; ++j) acc[j] = 0.f;
    float ps = 0.f;

    __syncthreads();

    for (int base = seg_start; base < seg_end; base += CHUNK) {
        const int na = min(CHUNK, seg_end - base);
        {
            const int nf4 = na * (D / 4);
            const float4* src = (const float4*)(atom_feas + (size_t)base * D);
            float4* dst = (float4*)fea_lds;
            for (int i = tid; i < nf4; i += 256) dst[i] = src[i];
        }
        __syncthreads();

        for (int pi = tid; pi < na * H; pi += 256) {
            const int aa = pi >> 5;
            const int hh = pi & 31;
            const float* fr = fea_lds + aa * D;
            float wvl = bk_lds[hh];
            #pragma unroll
            for (int k = 0; k < D; k += 4) {
                float4 f = *(const float4*)(fr + k);
                wvl += f.x * wk_lds[(k + 0) * H + hh];
                wvl += f.y * wk_lds[(k + 1) * H + hh];
                wvl += f.z * wk_lds[(k + 2) * H + hh];
                wvl += f.w * wk_lds[(k + 3) * H + hh];
            }
            w_lds[pi] = __expf(wvl);
        }
        __syncthreads();

        for (int aa = 0; aa < na; ++aa) {
            const float p = w_lds[aa * H + h];
            ps += p;
            const float* f = fea_lds + aa * D + grp * 8;
            #pragma unroll
            for (int j = 0; j < 8; ++j) acc[j] += f[j] * p;
        }
        __syncthreads();
    }

    const float inv = (ps > 0.f) ? 1.0f / ps : 0.f;
    float* og = out + (size_t)g * (D * H);
    #pragma unroll
    for (int j = 0; j < 8; ++j) og[(grp * 8 + j) * H + h] = acc[j] * inv;
}

extern "C" void kernel_launch(void* const* d_in, const int* in_sizes, int n_in,
                              void* d_out, int out_size, void* d_ws, size_t ws_size,
                              hipStream_t stream) {
    const float* atom_feas = (const float*)d_in[0];
    const float* Wk        = (const float*)d_in[1];
    const float* bk        = (const float*)d_in[2];
    // d_in[3] = atomic_numbers (unused by the reference)
    const int*   owner     = (const int*)d_in[4];
    const int n_atoms = in_sizes[4];
    float* out = (float*)d_out;

    const size_t bounds_bytes = 16384;
    const size_t f16_bytes = (size_t)n_atoms * D * 2;

    if (ws_size >= bounds_bytes + f16_bytes) {
        int*   bounds = (int*)d_ws;
        uint2* f16fea = (uint2*)((char*)d_ws + bounds_bytes);

        const int nf4 = n_atoms * (D / 4);
        convert_bounds_kernel<<<(nf4 + 255) / 256, 256, 0, stream>>>(
            atom_feas, owner, f16fea, bounds, n_atoms);
        crystal_kernel<<<NC, 128, 0, stream>>>(
            (const uint4*)f16fea, Wk, bk, bounds, out);
    } else {
        fused_kernel<<<NC, 256, 0, stream>>>(atom_feas, Wk, bk, owner, out, n_atoms);
    }
}

// Round 20
// 45.588 us; speedup vs baseline: 6.1189x; 1.1480x over previous
//
#include <hip/hip_runtime.h>

#define NC 2048
#define D 64
#define H 32

typedef __fp16 h2 __attribute__((ext_vector_type(2)));
typedef unsigned int u32;

#if __has_builtin(__builtin_amdgcn_fdot2)
#define FDOT2(a, b, c) __builtin_amdgcn_fdot2((a), (b), (c), false)
#else
#define FDOT2(a, b, c) ((c) + (float)(a)[0] * (float)(b)[0] + (float)(a)[1] * (float)(b)[1])
#endif
#define BC2(u) __builtin_bit_cast(h2, (u))

// ---------------- K1: segment bounds (owner sorted ascending) -------------
__global__ void bounds_kernel(const int* __restrict__ owner,
                              int* __restrict__ bounds, int n) {
    int i = blockIdx.x * blockDim.x + threadIdx.x;
    if (i >= n) return;
    int o  = owner[i];
    int op = (i == 0) ? -1 : owner[i - 1];
    for (int g = op + 1; g <= o; ++g) bounds[g] = i;
    if (i == n - 1)
        for (int g = o + 1; g <= NC; ++g) bounds[g] = n;
}

// ---- K2: R13 staging pipeline x R19 in-lane full dot ---------------------
// Evidence through R19: R13 (34.4us; chunked LDS staging + per-atom shfl)
// beats all global-direct variants. Its residual defect: the shfl is a DS op
// MID-dependency-chain -> lgkmcnt drain also flushes next atom's prefetched
// ds_reads. R20 = R13's verified staging (global->reg->fp16 pack->wave-
// private LDS dbuf, 1 chunk ahead) + R19's verified in-lane full dot:
// lane = (dg, h) holds FULL Wk col h (wkh[32]); per atom reads the full
// 128B fp16 row (8 uniform ds_read_b128, broadcast) -> logit in-lane, NO
// cross-lane/DS dependency mid-chain. Outer product: R19's value-select
// (static indices; rule-#20 safe). Per-lane es = complete wave denominator.
// Occupancy law: stage 4KB + part[65][61] 15.9KB = ~20.0KB -> exactly
// 8 blocks/CU -> 16 waves/CU -> 4 waves/EU -> VGPR cap 128 >= demand ~116.
__global__ __launch_bounds__(128)
void crystal_kernel(
    const float* __restrict__ atom_feas,
    const float* __restrict__ Wk,
    const float* __restrict__ bk,
    const int* __restrict__ bounds,
    float* __restrict__ out,
    int n)
{
    __shared__ __align__(16) u32 stage[2][2][8][32];   // 4 KB fp16 staging
    __shared__ float part[65][61];                     // 15.9 KB combine buf

    const int g    = blockIdx.x;
    const int tid  = threadIdx.x;
    const int lane = tid & 63;
    const int wv   = tid >> 6;          // 0 or 1
    const int h    = lane & 31;
    const int dg   = lane >> 5;
    const bool hi  = (dg != 0);

    // full Wk column h as packed half2 (32 regs)
    h2 wkh[32];
    #pragma unroll
    for (int j = 0; j < 32; ++j)
        wkh[j] = __builtin_amdgcn_cvt_pkrtz(Wk[(2 * j) * H + h],
                                            Wk[(2 * j + 1) * H + h]);
    const float bkv = bk[h];

    const int s   = bounds[g];
    const int e   = bounds[g + 1];
    const int per = (e - s + 1) >> 1;   // contiguous half per wave
    const int a0  = s + wv * per;
    const int ae  = min(a0 + per, e);

    float acc[32];
    #pragma unroll
    for (int j = 0; j < 32; ++j) acc[j] = 0.f;
    float es = 0.f;

    if (a0 < ae) {
        const int nchunk = (ae - a0 + 7) >> 3;
        const int maxf4  = n * 16 - 1;            // clamp staging reads in-bounds
        const float4* af4 = (const float4*)atom_feas;

        int cb = a0;                               // prologue: chunk 0 -> regs
        float4 r0 = af4[min(cb * 16 + lane,      maxf4)];
        float4 r1 = af4[min(cb * 16 + lane + 64, maxf4)];

        for (int c = 0; c < nchunk; ++c) {
            {   // pack chunk c to fp16, write to wave-private LDS buffer
                uint2* sw = (uint2*)stage[wv][c & 1];
                const h2 p0 = __builtin_amdgcn_cvt_pkrtz(r0.x, r0.y);
                const h2 p1 = __builtin_amdgcn_cvt_pkrtz(r0.z, r0.w);
                const h2 p2 = __builtin_amdgcn_cvt_pkrtz(r1.x, r1.y);
                const h2 p3 = __builtin_amdgcn_cvt_pkrtz(r1.z, r1.w);
                uint2 w0, w1;
                w0.x = __builtin_bit_cast(u32, p0); w0.y = __builtin_bit_cast(u32, p1);
                w1.x = __builtin_bit_cast(u32, p2); w1.y = __builtin_bit_cast(u32, p3);
                const int slot = lane & 15, arow = lane >> 4;
                sw[arow * 16 + slot]       = w0;   // atoms 0..3 of chunk
                sw[(arow + 4) * 16 + slot] = w1;   // atoms 4..7
            }
            const int nb = cb + 8;
            if (c + 1 < nchunk) {                  // issue chunk c+1 loads now;
                r0 = af4[min(nb * 16 + lane,      maxf4)];  // fly during compute
                r1 = af4[min(nb * 16 + lane + 64, maxf4)];
            }

            const uint4* srbase = (const uint4*)stage[wv][c & 1];
            #pragma unroll 2
            for (int i = 0; i < 8; ++i) {
                const int aa = cb + i;
                const uint4* sr = srbase + i * 8;   // full 128B fp16 row
                const uint4 x0 = sr[0], x1 = sr[1], x2 = sr[2], x3 = sr[3];
                const uint4 x4 = sr[4], x5 = sr[5], x6 = sr[6], x7 = sr[7];

                // full 64-dim dot, 4 independent chains, in-lane (no shfl)
                float q0 = 0.f, q1 = 0.f, q2 = 0.f, q3 = 0.f;
                q0 = FDOT2(BC2(x0.x), wkh[0],  q0);
                q1 = FDOT2(BC2(x0.y), wkh[1],  q1);
                q2 = FDOT2(BC2(x0.z), wkh[2],  q2);
                q3 = FDOT2(BC2(x0.w), wkh[3],  q3);
                q0 = FDOT2(BC2(x1.x), wkh[4],  q0);
                q1 = FDOT2(BC2(x1.y), wkh[5],  q1);
                q2 = FDOT2(BC2(x1.z), wkh[6],  q2);
                q3 = FDOT2(BC2(x1.w), wkh[7],  q3);
                q0 = FDOT2(BC2(x2.x), wkh[8],  q0);
                q1 = FDOT2(BC2(x2.y), wkh[9],  q1);
                q2 = FDOT2(BC2(x2.z), wkh[10], q2);
                q3 = FDOT2(BC2(x2.w), wkh[11], q3);
                q0 = FDOT2(BC2(x3.x), wkh[12], q0);
                q1 = FDOT2(BC2(x3.y), wkh[13], q1);
                q2 = FDOT2(BC2(x3.z), wkh[14], q2);
                q3 = FDOT2(BC2(x3.w), wkh[15], q3);
                q0 = FDOT2(BC2(x4.x), wkh[16], q0);
                q1 = FDOT2(BC2(x4.y), wkh[17], q1);
                q2 = FDOT2(BC2(x4.z), wkh[18], q2);
                q3 = FDOT2(BC2(x4.w), wkh[19], q3);
                q0 = FDOT2(BC2(x5.x), wkh[20], q0);
                q1 = FDOT2(BC2(x5.y), wkh[21], q1);
                q2 = FDOT2(BC2(x5.z), wkh[22], q2);
                q3 = FDOT2(BC2(x5.w), wkh[23], q3);
                q0 = FDOT2(BC2(x6.x), wkh[24], q0);
                q1 = FDOT2(BC2(x6.y), wkh[25], q1);
                q2 = FDOT2(BC2(x6.z), wkh[26], q2);
                q3 = FDOT2(BC2(x6.w), wkh[27], q3);
                q0 = FDOT2(BC2(x7.x), wkh[28], q0);
                q1 = FDOT2(BC2(x7.y), wkh[29], q1);
                q2 = FDOT2(BC2(x7.z), wkh[30], q2);
                q3 = FDOT2(BC2(x7.w), wkh[31], q3);

                const float p = (aa < ae)
                    ? __expf((q0 + q1) + (q2 + q3) + bkv) : 0.f;
                es += p;

                // value-select this lane's dg-half (static indices)
                const uint4 y0 = hi ? x4 : x0;
                const uint4 y1 = hi ? x5 : x1;
                const uint4 y2 = hi ? x6 : x2;
                const uint4 y3 = hi ? x7 : x3;
#define OUTQ(Y, base)                                     \
                { const h2 ha = BC2(Y.x); const h2 hb = BC2(Y.y); \
                  const h2 hc = BC2(Y.z); const h2 hd = BC2(Y.w); \
                  acc[base + 0] += (float)ha[0] * p;              \
                  acc[base + 1] += (float)ha[1] * p;              \
                  acc[base + 2] += (float)hb[0] * p;              \
                  acc[base + 3] += (float)hb[1] * p;              \
                  acc[base + 4] += (float)hc[0] * p;              \
                  acc[base + 5] += (float)hc[1] * p;              \
                  acc[base + 6] += (float)hd[0] * p;              \
                  acc[base + 7] += (float)hd[1] * p; }
                OUTQ(y0, 0) OUTQ(y1, 8) OUTQ(y2, 16) OUTQ(y3, 24)
#undef OUTQ
            }
            cb = nb;
        }
    }

    // ---- cross-wave combine (once per block; R19-verified pattern)
    if (wv == 1) {
        #pragma unroll
        for (int m = 0; m < 32; ++m) part[dg * 32 + m][h] = acc[m];
        if (lane < 32) part[64][lane] = es;
    }
    __syncthreads();
    if (wv == 0) {
        const float den = es + part[64][h];
        const float inv = (den > 0.f) ? 1.0f / den : 0.f;
        float* og = out + (size_t)g * (D * H);
        #pragma unroll
        for (int m = 0; m < 32; ++m)
            og[(dg * 32 + m) * H + h] = (acc[m] + part[dg * 32 + m][h]) * inv;
    }
}

// ---- Fallback (ws too small): known-good fused kernel --------------------
#define CHUNK 64
__global__ __launch_bounds__(256) void fused_kernel(
    const float* __restrict__ atom_feas,
    const float* __restrict__ Wk,
    const float* __restrict__ bk,
    const int* __restrict__ owner,
    float* __restrict__ out,
    int n_atoms)
{
    __shared__ float fea_lds[CHUNK * D];
    __shared__ float w_lds[CHUNK * H];
    __shared__ float wk_lds[D * H];
    __shared__ float bk_lds[H];

    const int g   = blockIdx.x;
    const int tid = threadIdx.x;
    const int h   = tid & 31;
    const int grp = tid >> 5;

    for (int i = tid; i < D * H; i += 256) wk_lds[i] = Wk[i];
    if (tid < H) bk_lds[tid] = bk[tid];

    int lo = 0, hi = n_atoms;
    while (lo < hi) { int mid = (lo + hi) >> 1; if (owner[mid] < g) lo = mid + 1; else hi = mid; }
    const int seg_start = lo;
    hi = n_atoms;
    while (lo < hi) { int mid = (lo + hi) >> 1; if (owner[mid] < g + 1) lo = mid + 1; else hi = mid; }
    const int seg_end = lo;

    float acc[8];
    #pragma unroll
    for (int j = 0; j < 8; ++j) acc[j] = 0.f;
    float ps = 0.f;

    __syncthreads();

    for (int base = seg_start; base < seg_end; base += CHUNK) {
        const int na = min(CHUNK, seg_end - base);
        {
            const int nf4 = na * (D / 4);
            const float4* src = (const float4*)(atom_feas + (size_t)base * D);
            float4* dst = (float4*)fea_lds;
            for (int i = tid; i < nf4; i += 256) dst[i] = src[i];
        }
        __syncthreads();

        for (int pi = tid; pi < na * H; pi += 256) {
            const int aa = pi >> 5;
            const int hh = pi & 31;
            const float* fr = fea_lds + aa * D;
            float wvl = bk_lds[hh];
            #pragma unroll
            for (int k = 0; k < D; k += 4) {
                float4 f = *(const float4*)(fr + k);
                wvl += f.x * wk_lds[(k + 0) * H + hh];
                wvl += f.y * wk_lds[(k + 1) * H + hh];
                wvl += f.z * wk_lds[(k + 2) * H + hh];
                wvl += f.w * wk_lds[(k + 3) * H + hh];
            }
            w_lds[pi] = __expf(wvl);
        }
        __syncthreads();

        for (int aa = 0; aa < na; ++aa) {
            const float p = w_lds[aa * H + h];
            ps += p;
            const float* f = fea_lds + aa * D + grp * 8;
            #pragma unroll
            for (int j = 0; j < 8; ++j) acc[j] += f[j] * p;
        }
        __syncthreads();
    }

    const float inv = (ps > 0.f) ? 1.0f / ps : 0.f;
    float* og = out + (size_t)g * (D * H);
    #pragma unroll
    for (int j = 0; j < 8; ++j) og[(grp * 8 + j) * H + h] = acc[j] * inv;
}

extern "C" void kernel_launch(void* const* d_in, const int* in_sizes, int n_in,
                              void* d_out, int out_size, void* d_ws, size_t ws_size,
                              hipStream_t stream) {
    const float* atom_feas = (const float*)d_in[0];
    const float* Wk        = (const float*)d_in[1];
    const float* bk        = (const float*)d_in[2];
    // d_in[3] = atomic_numbers (unused by the reference)
    const int*   owner     = (const int*)d_in[4];
    const int n_atoms = in_sizes[4];
    float* out = (float*)d_out;

    if (ws_size >= (NC + 1) * sizeof(int)) {
        int* bounds = (int*)d_ws;
        bounds_kernel<<<(n_atoms + 255) / 256, 256, 0, stream>>>(owner, bounds, n_atoms);
        crystal_kernel<<<NC, 128, 0, stream>>>(atom_feas, Wk, bk, bounds, out, n_atoms);
    } else {
        fused_kernel<<<NC, 256, 0, stream>>>(atom_feas, Wk, bk, owner, out, n_atoms);
    }
}

// Round 21
// 41.243 us; speedup vs baseline: 6.7635x; 1.1053x over previous
//
#include <hip/hip_runtime.h>

#define NC 2048
#define D 64
#define H 32
#define FPAD 68

typedef __fp16 h2 __attribute__((ext_vector_type(2)));
typedef unsigned int u32;

#define BCH(u) __builtin_bit_cast(h2, (u))

// ---- K1: atom-parallel logits e=exp(fea.Wk+bk) -> fp16, + fused bounds ---
// Structure verified in R2/R3 (f32 path): 64 atoms/block, thread=(atom,
// 4-head group of 8), fea staged f32 with pad-68, Wk in LDS. Output packed
// fp16 pairs (e in [0,~250], fp16 rel err ~1e-3 -> absmax +~3e-3, safe).
__global__ __launch_bounds__(256) void logits_kernel(
    const float* __restrict__ atom_feas,
    const float* __restrict__ Wk,
    const float* __restrict__ bk,
    const int* __restrict__ owner,
    u32* __restrict__ e16,              // [n][16] u32 = 32 fp16 heads/atom
    int* __restrict__ bounds,
    int n)
{
    __shared__ float fea_lds[64 * FPAD];  // 17 KB
    __shared__ float wk_lds[D * H];       // 8 KB
    __shared__ float bk_lds[H];

    const int tid  = threadIdx.x;
    const int base = blockIdx.x * 64;
    const int na   = min(64, n - base);

    // fused segment-bounds (owner sorted; grid covers n: 1563*256 > 100k)
    const int gi = blockIdx.x * 256 + tid;
    if (gi < n) {
        const int o  = owner[gi];
        const int op = (gi == 0) ? -1 : owner[gi - 1];
        for (int g = op + 1; g <= o; ++g) bounds[g] = gi;
        if (gi == n - 1)
            for (int g = o + 1; g <= NC; ++g) bounds[g] = n;
    }

    for (int i = tid; i < D * H; i += 256) wk_lds[i] = Wk[i];
    if (tid < H) bk_lds[tid] = bk[tid];

    {
        const float4* src = (const float4*)(atom_feas + (size_t)base * D);
        const int nf4 = na * (D / 4);
        for (int i = tid; i < nf4; i += 256) {
            const int a = i >> 4, c2 = i & 15;
            *(float4*)(fea_lds + a * FPAD + c2 * 4) = src[i];
        }
    }
    __syncthreads();

    const int a  = tid >> 2;          // 0..63
    const int h0 = (tid & 3) * 8;     // 0,8,16,24
    if (a < na) {
        float acc[8];
        #pragma unroll
        for (int j = 0; j < 8; ++j) acc[j] = bk_lds[h0 + j];

        const float* fr = fea_lds + a * FPAD;
        #pragma unroll
        for (int k = 0; k < D; k += 4) {
            const float4 f = *(const float4*)(fr + k);
            #pragma unroll
            for (int r = 0; r < 4; ++r) {
                const float fv = (&f.x)[r];
                const float4 w0 = *(const float4*)(wk_lds + (k + r) * H + h0);
                const float4 w1 = *(const float4*)(wk_lds + (k + r) * H + h0 + 4);
                acc[0] += fv * w0.x; acc[1] += fv * w0.y;
                acc[2] += fv * w0.z; acc[3] += fv * w0.w;
                acc[4] += fv * w1.x; acc[5] += fv * w1.y;
                acc[6] += fv * w1.z; acc[7] += fv * w1.w;
            }
        }
        uint4 pk;
        pk.x = __builtin_bit_cast(u32, __builtin_amdgcn_cvt_pkrtz(__expf(acc[0]), __expf(acc[1])));
        pk.y = __builtin_bit_cast(u32, __builtin_amdgcn_cvt_pkrtz(__expf(acc[2]), __expf(acc[3])));
        pk.z = __builtin_bit_cast(u32, __builtin_amdgcn_cvt_pkrtz(__expf(acc[4]), __expf(acc[5])));
        pk.w = __builtin_bit_cast(u32, __builtin_amdgcn_cvt_pkrtz(__expf(acc[6]), __expf(acc[7])));
        *(uint4*)(e16 + (size_t)(base + a) * 16 + (tid & 3) * 4) = pk;
    }
}

// ---- K2: per-crystal readout, NO dot/shfl/exp in loop --------------------
// R20 lesson: the logit dot chain (16-32 FDOT2 + shfl + exp per atom) was
// the dominant in-loop dependency. Here p is PRECOMPUTED (K1): per atom the
// lane does 1 LDS u32 read + value-select + 32 FMA. R13-verified skeleton:
// 2 waves/crystal (contiguous halves), chunked staging global->reg->LDS
// (fea f32->fp16 pack + e fp16 passthrough), wave-private double buffer,
// prefetch 1 chunk ahead, per-lane es = wave denominator, R13 combine.
// Occupancy law: LDS 14.7KB -> 10 blocks/CU -> 5 waves/EU -> VGPR cap ~102
// >= demand ~75 -> no spill. All register indices static (rule #20).
__global__ __launch_bounds__(128)
void readout_kernel(
    const float* __restrict__ atom_feas,
    const u32* __restrict__ e16,
    const int* __restrict__ bounds,
    float* __restrict__ out,
    int n)
{
    __shared__ __align__(16) u32 stage[2][2][8][32];   // 4 KB fea fp16
    __shared__ __align__(8)  uint2 estage[2][2][64];   // 2 KB e fp16
    __shared__ float part[64][33];                     // 8.4 KB combine

    const int g    = blockIdx.x;
    const int tid  = threadIdx.x;
    const int lane = tid & 63;
    const int wv   = tid >> 6;          // 0 or 1
    const int h    = lane & 31;
    const int dg   = lane >> 5;
    const int d0   = dg * 32;

    const int s   = bounds[g];
    const int e   = bounds[g + 1];
    const int per = (e - s + 1) >> 1;   // contiguous half per wave
    const int a0  = s + wv * per;
    const int ae  = min(a0 + per, e);

    float acc[32];
    #pragma unroll
    for (int j = 0; j < 32; ++j) acc[j] = 0.f;
    float es = 0.f;

    if (a0 < ae) {
        const int nchunk = (ae - a0 + 7) >> 3;
        const int maxf4  = n * 16 - 1;
        const int maxe2  = n * 8 - 1;
        const float4* af4 = (const float4*)atom_feas;
        const uint2*  e2  = (const uint2*)e16;

        int cb = a0;                    // prologue: chunk 0 -> regs
        float4 r0 = af4[min(cb * 16 + lane,      maxf4)];
        float4 r1 = af4[min(cb * 16 + lane + 64, maxf4)];
        uint2  eu = e2 [min(cb * 8  + lane,      maxe2)];

        for (int c = 0; c < nchunk; ++c) {
            {   // stage chunk c: fea pack->fp16 (R13-verified layout), e raw
                uint2* sw = (uint2*)stage[wv][c & 1];
                const h2 p0 = __builtin_amdgcn_cvt_pkrtz(r0.x, r0.y);
                const h2 p1 = __builtin_amdgcn_cvt_pkrtz(r0.z, r0.w);
                const h2 p2 = __builtin_amdgcn_cvt_pkrtz(r1.x, r1.y);
                const h2 p3 = __builtin_amdgcn_cvt_pkrtz(r1.z, r1.w);
                uint2 w0, w1;
                w0.x = __builtin_bit_cast(u32, p0); w0.y = __builtin_bit_cast(u32, p1);
                w1.x = __builtin_bit_cast(u32, p2); w1.y = __builtin_bit_cast(u32, p3);
                const int slot = lane & 15, arow = lane >> 4;
                sw[arow * 16 + slot]       = w0;
                sw[(arow + 4) * 16 + slot] = w1;
                estage[wv][c & 1][lane] = eu;
            }
            const int nb = cb + 8;
            if (c + 1 < nchunk) {       // prefetch chunk c+1 (flies over compute)
                r0 = af4[min(nb * 16 + lane,      maxf4)];
                r1 = af4[min(nb * 16 + lane + 64, maxf4)];
                eu = e2 [min(nb * 8  + lane,      maxe2)];
            }

            const uint4* srbase = (const uint4*)stage[wv][c & 1];
            const u32*   ep     = (const u32*)estage[wv][c & 1];
            #pragma unroll 2
            for (int i = 0; i < 8; ++i) {
                const int aa = cb + i;
                // p for (atom aa, head h): 1 LDS u32 + value-select
                const u32 ew = ep[i * 16 + (h >> 1)];
                const u32 sel = (h & 1) ? (ew >> 16) : (ew & 0xffffu);
                float p = (float)__builtin_bit_cast(__fp16, (unsigned short)sel);
                p = (aa < ae) ? p : 0.f;
                es += p;

                // this lane's dg-half row (R13-verified addressing)
                const uint4* sr = srbase + i * 8 + dg * 4;
                const uint4 x0 = sr[0], x1 = sr[1], x2 = sr[2], x3 = sr[3];
#define OUTQ(Y, base)                                     \
                { const h2 ha = BCH(Y.x); const h2 hb = BCH(Y.y); \
                  const h2 hc = BCH(Y.z); const h2 hd = BCH(Y.w); \
                  acc[base + 0] += (float)ha[0] * p;              \
                  acc[base + 1] += (float)ha[1] * p;              \
                  acc[base + 2] += (float)hb[0] * p;              \
                  acc[base + 3] += (float)hb[1] * p;              \
                  acc[base + 4] += (float)hc[0] * p;              \
                  acc[base + 5] += (float)hc[1] * p;              \
                  acc[base + 6] += (float)hd[0] * p;              \
                  acc[base + 7] += (float)hd[1] * p; }
                OUTQ(x0, 0) OUTQ(x1, 8) OUTQ(x2, 16) OUTQ(x3, 24)
#undef OUTQ
            }
            cb = nb;
        }
    }

    // ---- cross-wave combine (R13-verified)
    if (wv == 1) {
        #pragma unroll
        for (int j = 0; j < 32; ++j) part[lane][j] = acc[j];
        part[lane][32] = es;
    }
    __syncthreads();
    if (wv == 0) {
        #pragma unroll
        for (int j = 0; j < 32; ++j) acc[j] += part[lane][j];
        es += part[lane][32];
        const float inv = (es > 0.f) ? 1.0f / es : 0.f;
        float* og = out + (size_t)g * (D * H);
        #pragma unroll
        for (int j = 0; j < 32; ++j)
            og[(d0 + j) * H + h] = acc[j] * inv;   // 2x128B per instr, coalesced
    }
}

// ---- Fallback (ws too small): known-good fused kernel --------------------
#define CHUNK 64
__global__ __launch_bounds__(256) void fused_kernel(
    const float* __restrict__ atom_feas,
    const float* __restrict__ Wk,
    const float* __restrict__ bk,
    const int* __restrict__ owner,
    float* __restrict__ out,
    int n_atoms)
{
    __shared__ float fea_lds[CHUNK * D];
    __shared__ float w_lds[CHUNK * H];
    __shared__ float wk_lds[D * H];
    __shared__ float bk_lds[H];

    const int g   = blockIdx.x;
    const int tid = threadIdx.x;
    const int h   = tid & 31;
    const int grp = tid >> 5;

    for (int i = tid; i < D * H; i += 256) wk_lds[i] = Wk[i];
    if (tid < H) bk_lds[tid] = bk[tid];

    int lo = 0, hi = n_atoms;
    while (lo < hi) { int mid = (lo + hi) >> 1; if (owner[mid] < g) lo = mid + 1; else hi = mid; }
    const int seg_start = lo;
    hi = n_atoms;
    while (lo < hi) { int mid = (lo + hi) >> 1; if (owner[mid] < g + 1) lo = mid + 1; else hi = mid; }
    const int seg_end = lo;

    float acc[8];
    #pragma unroll
    for (int j = 0; j < 8; ++j) acc[j] = 0.f;
    float ps = 0.f;

    __syncthreads();

    for (int base = seg_start; base < seg_end; base += CHUNK) {
        const int na = min(CHUNK, seg_end - base);
        {
            const int nf4 = na * (D / 4);
            const float4* src = (const float4*)(atom_feas + (size_t)base * D);
            float4* dst = (float4*)fea_lds;
            for (int i = tid; i < nf4; i += 256) dst[i] = src[i];
        }
        __syncthreads();

        for (int pi = tid; pi < na * H; pi += 256) {
            const int aa = pi >> 5;
            const int hh = pi & 31;
            const float* fr = fea_lds + aa * D;
            float wvl = bk_lds[hh];
            #pragma unroll
            for (int k = 0; k < D; k += 4) {
                float4 f = *(const float4*)(fr + k);
                wvl += f.x * wk_lds[(k + 0) * H + hh];
                wvl += f.y * wk_lds[(k + 1) * H + hh];
                wvl += f.z * wk_lds[(k + 2) * H + hh];
                wvl += f.w * wk_lds[(k + 3) * H + hh];
            }
            w_lds[pi] = __expf(wvl);
        }
        __syncthreads();

        for (int aa = 0; aa < na; ++aa) {
            const float p = w_lds[aa * H + h];
            ps += p;
            const float* f = fea_lds + aa * D + grp * 8;
            #pragma unroll
            for (int j = 0; j < 8; ++j) acc[j] += f[j] * p;
        }
        __syncthreads();
    }

    const float inv = (ps > 0.f) ? 1.0f / ps : 0.f;
    float* og = out + (size_t)g * (D * H);
    #pragma unroll
    for (int j = 0; j < 8; ++j) og[(grp * 8 + j) * H + h] = acc[j] * inv;
}

extern "C" void kernel_launch(void* const* d_in, const int* in_sizes, int n_in,
                              void* d_out, int out_size, void* d_ws, size_t ws_size,
                              hipStream_t stream) {
    const float* atom_feas = (const float*)d_in[0];
    const float* Wk        = (const float*)d_in[1];
    const float* bk        = (const float*)d_in[2];
    // d_in[3] = atomic_numbers (unused by the reference)
    const int*   owner     = (const int*)d_in[4];
    const int n_atoms = in_sizes[4];
    float* out = (float*)d_out;

    const size_t bounds_bytes = 16384;
    const size_t e_bytes = (size_t)n_atoms * H * 2;   // fp16 e-matrix, 6.4 MB

    if (ws_size >= bounds_bytes + e_bytes) {
        int* bounds = (int*)d_ws;
        u32* e16    = (u32*)((char*)d_ws + bounds_bytes);

        const int nb = (n_atoms + 63) / 64;
        logits_kernel<<<nb, 256, 0, stream>>>(atom_feas, Wk, bk, owner,
                                              e16, bounds, n_atoms);
        readout_kernel<<<NC, 128, 0, stream>>>(atom_feas, e16, bounds,
                                               out, n_atoms);
    } else {
        fused_kernel<<<NC, 256, 0, stream>>>(atom_feas, Wk, bk, owner, out, n_atoms);
    }
}